// Round 11
// baseline (6795.226 us; speedup 1.0000x reference)
//
#include <hip/hip_runtime.h>

#define N_PTS 16384
#define ROWF  131        // 3 coords + 128 features
#define M_OUT 4096       // N / POOL
#define KNN   16
#define FPS_T 1024       // fps threads (16 waves)
#define SORT_T 1024

typedef unsigned long long u64;
typedef float f32x2 __attribute__((ext_vector_type(2)));

// spread 4 bits -> every 3rd bit (Morton interleave LUT)
__device__ __constant__ unsigned short c_spread4[16] =
  {0,1,8,9,64,65,72,73,512,513,520,521,576,577,584,585};

__device__ __forceinline__ int cell_of(float x, float y, float z) {
  int ix = (int)floorf((x + 4.0f) * 2.0f); ix = ix < 0 ? 0 : (ix > 15 ? 15 : ix);
  int iy = (int)floorf((y + 4.0f) * 2.0f); iy = iy < 0 ? 0 : (iy > 15 ? 15 : iy);
  int iz = (int)floorf((z + 4.0f) * 2.0f); iz = iz < 0 ? 0 : (iz > 15 ? 15 : iz);
  return (int)c_spread4[ix] | ((int)c_spread4[iy] << 1) | ((int)c_spread4[iz] << 2);
}

// u64 max-combine with a DPP-moved partner (VALU-speed cross-lane).
template <int CTRL, int ROW_MASK>
__device__ __forceinline__ u64 kmax_dpp(u64 k) {
  const int lo = (int)(unsigned)k, hi = (int)(unsigned)(k >> 32);
  const int nlo = __builtin_amdgcn_update_dpp(lo, lo, CTRL, ROW_MASK, 0xf, false);
  const int nhi = __builtin_amdgcn_update_dpp(hi, hi, CTRL, ROW_MASK, 0xf, false);
  const u64 nk = ((u64)(unsigned)nhi << 32) | (unsigned)nlo;
  return nk > k ? nk : k;
}

// ---------------------------------------------------------------------------
// 1) Extract coords into packed float4 (x,y,z,unused), orig-index order.
// ---------------------------------------------------------------------------
__global__ void prep_kernel(const float* __restrict__ x,
                            float4* __restrict__ coords4) {
  const int p = blockIdx.x * blockDim.x + threadIdx.x;
  if (p < N_PTS) {
    coords4[p] = make_float4(x[p * ROWF + 0], x[p * ROWF + 1],
                             x[p * ROWF + 2], 0.0f);
  }
}

// ---------------------------------------------------------------------------
// 2) Counting-sort by Morton cell (4096 cells), one 1024-thread block.
//    slot-major packed float4 (x,y,z,bitcast(origIdx)); within-cell scatter
//    order racy but output-invariant.
// ---------------------------------------------------------------------------
__global__ __launch_bounds__(1024, 1)
void sort_kernel(const float4* __restrict__ coords4, float4* __restrict__ gP4) {
  __shared__ unsigned int sh[4096];
  __shared__ unsigned int sws[16];
  const int tid = threadIdx.x, lane = tid & 63, wid = tid >> 6;

#pragma unroll
  for (int i = 0; i < 4; ++i) sh[tid * 4 + i] = 0;
  __syncthreads();

  int cel[16];
#pragma unroll
  for (int j = 0; j < 16; ++j) {
    const float4 v = coords4[tid + SORT_T * j];
    const int c = cell_of(v.x, v.y, v.z);
    cel[j] = c;
    atomicAdd(&sh[c], 1u);
  }
  __syncthreads();

  const unsigned h0 = sh[tid * 4 + 0], h1 = sh[tid * 4 + 1];
  const unsigned h2 = sh[tid * 4 + 2], h3 = sh[tid * 4 + 3];
  const unsigned tsum = h0 + h1 + h2 + h3;
  unsigned inc = tsum;
#pragma unroll
  for (int off = 1; off < 64; off <<= 1) {
    const unsigned v = __shfl_up(inc, off);
    if (lane >= off) inc += v;
  }
  if (lane == 63) sws[wid] = inc;
  __syncthreads();
  if (tid == 0) {
    unsigned run = 0;
#pragma unroll
    for (int w = 0; w < 16; ++w) { const unsigned t = sws[w]; sws[w] = run; run += t; }
  }
  __syncthreads();
  const unsigned base = sws[wid] + inc - tsum;
  sh[tid * 4 + 0] = base;
  sh[tid * 4 + 1] = base + h0;
  sh[tid * 4 + 2] = base + h0 + h1;
  sh[tid * 4 + 3] = base + h0 + h1 + h2;
  __syncthreads();

#pragma unroll
  for (int j = 0; j < 16; ++j) {
    const int p = tid + SORT_T * j;
    const float4 v = coords4[p];
    const unsigned rk = atomicAdd(&sh[cel[j]], 1u);
    const int slot = (int)(((rk & 15u) << 10) | (rk >> 4));
    gP4[slot] = make_float4(v.x, v.y, v.z, __int_as_float(p));
  }
}

// ---------------------------------------------------------------------------
// 3) FPS v11: arch-VGPR-pinned state + packed-f32 pairs + DPP reductions.
//    Round-10 tell: VGPR_Count=56 < 80 persistent values => compiler parked
//    state in AGPRs / L2-remat, taxing every access. asm("" : "+v"(x)) pins
//    each value as an opaque arch-VGPR def (unrematerializable, 'v' class).
//    Update math on f32x2 pairs under fp contract(off): elementwise IEEE
//    RTNE == the __fmul_rn/__fadd_rn chain bitwise (a-b == a+(-b) exactly);
//    backend may emit v_pk_add/mul_f32 (halves issue). Wave u64 max via 6
//    DPP levels (lane 63 ends with full max -> direct LDS write, no
//    readlane); cross-wave ds_read + 4 DPP; ONE barrier/step. Per-lane
//    chunk spheres + ballot skip, same conservative margins as rounds 4-10
//    (skip => provably every fminf(md,d2) is a no-op => bitwise-identical
//    trajectory). Key=(md_bits<<32)|(16383-idx): max md, tie -> lowest idx.
// ---------------------------------------------------------------------------
#define REP16(F) F(0) F(1) F(2) F(3) F(4) F(5) F(6) F(7) \
                 F(8) F(9) F(10) F(11) F(12) F(13) F(14) F(15)
#define REP8P(F) F(0,0,1) F(1,2,3) F(2,4,5) F(3,6,7) \
                 F(4,8,9) F(5,10,11) F(6,12,13) F(7,14,15)

__global__
__attribute__((amdgpu_flat_work_group_size(FPS_T, FPS_T)))
__attribute__((amdgpu_waves_per_eu(4, 4)))
void fps_kernel(const float4* __restrict__ coords4,
                const float4* __restrict__ gP4, float* __restrict__ out) {
#pragma clang fp contract(off)
  __shared__ u64 s_wkey[2][16];
  const int tid = threadIdx.x, lane = tid & 63, wid = tid >> 6;

#define FPS_DECLP(t,a,b) f32x2 PX##t, PY##t, PZ##t;
  REP8P(FPS_DECLP)
#undef FPS_DECLP
#define FPS_DECLS(j) float md##j; unsigned ni##j;
  REP16(FPS_DECLS)
#undef FPS_DECLS

#define FPS_INITP(t,a,b) {                                                 \
    const float4 va = gP4[(a << 10) + tid];                                \
    const float4 vb = gP4[(b << 10) + tid];                                \
    PX##t = (f32x2){va.x, vb.x};                                           \
    PY##t = (f32x2){va.y, vb.y};                                           \
    PZ##t = (f32x2){va.z, vb.z};                                           \
    ni##a = (unsigned)__float_as_int(va.w);                                \
    ni##b = (unsigned)__float_as_int(vb.w);                                \
    md##a = __int_as_float(0x7f800000);                                    \
    md##b = __int_as_float(0x7f800000); }
  REP8P(FPS_INITP)
#undef FPS_INITP

  // pin persistent state into arch VGPRs (opaque defs: no remat, no AGPR)
  asm volatile("" : "+v"(PX0), "+v"(PY0), "+v"(PZ0), "+v"(PX1), "+v"(PY1),
                    "+v"(PZ1), "+v"(PX2), "+v"(PY2), "+v"(PZ2), "+v"(PX3),
                    "+v"(PY3), "+v"(PZ3));
  asm volatile("" : "+v"(PX4), "+v"(PY4), "+v"(PZ4), "+v"(PX5), "+v"(PY5),
                    "+v"(PZ5), "+v"(PX6), "+v"(PY6), "+v"(PZ6), "+v"(PX7),
                    "+v"(PY7), "+v"(PZ7));
  asm volatile("" : "+v"(ni0), "+v"(ni1), "+v"(ni2), "+v"(ni3), "+v"(ni4),
                    "+v"(ni5), "+v"(ni6), "+v"(ni7), "+v"(ni8), "+v"(ni9),
                    "+v"(ni10), "+v"(ni11), "+v"(ni12), "+v"(ni13),
                    "+v"(ni14), "+v"(ni15));

  // per-lane chunk bounding sphere over this lane's 16 compact points
  float sx = 0.f, sy = 0.f, sz = 0.f;
#define FPS_ACCP(t,a,b) { sx += PX##t.x + PX##t.y;                         \
    sy += PY##t.x + PY##t.y; sz += PZ##t.x + PZ##t.y; }
  REP8P(FPS_ACCP)
#undef FPS_ACCP
  const float ccx = sx * (1.0f / 16.0f), ccy = sy * (1.0f / 16.0f),
              ccz = sz * (1.0f / 16.0f);
  float cr2 = 0.f;
#define FPS_RADP(t,a,b) {                                                  \
    const float dxa = PX##t.x - ccx, dya = PY##t.x - ccy,                  \
                dza = PZ##t.x - ccz;                                       \
    cr2 = fmaxf(cr2, dxa * dxa + dya * dya + dza * dza);                   \
    const float dxb = PX##t.y - ccx, dyb = PY##t.y - ccy,                  \
                dzb = PZ##t.y - ccz;                                       \
    cr2 = fmaxf(cr2, dxb * dxb + dyb * dyb + dzb * dzb); }
  REP8P(FPS_RADP)
#undef FPS_RADP
  const float cr = sqrtf(cr2) * 1.000001f + 1e-6f;

  float thr = __int_as_float(0x7f800000);  // cached (cr+sqrt(m*1.0001))^2; +inf => dirty
  u64 wkk = 0;                             // persistent butterfly result (lane 63 = wave max)

  const float4 q0 = coords4[0];
  float qx = q0.x, qy = q0.y, qz = q0.z;
  if (tid == 0) { out[0] = qx; out[1] = qy; out[2] = qz; }

  for (int s = 1; s < M_OUT; ++s) {
    // per-lane chunk prune test; wave updates iff ANY lane dirty
    const float dqx = qx - ccx, dqy = qy - ccy, dqz = qz - ccz;
    const float dd = dqx * dqx + dqy * dqy + dqz * dqz;
    const bool ldirty = (dd * 0.999999f <= thr);

    if (__ballot(ldirty)) {                      // wave-uniform branch
      const f32x2 QX = {qx, qx}, QY = {qy, qy}, QZ = {qz, qz};
      float ma = 0.f, mb = 0.f;
#define FPS_UPDP(t,a,b) {                                                  \
      const f32x2 dx = PX##t - QX;                                        \
      const f32x2 dy = PY##t - QY;                                        \
      const f32x2 dz = PZ##t - QZ;                                        \
      const f32x2 xx = dx * dx;                                           \
      const f32x2 yy = dy * dy;                                           \
      const f32x2 zz = dz * dz;                                           \
      const f32x2 ss = xx + yy;                                           \
      const f32x2 d2 = ss + zz;                                           \
      const float nma = fminf(md##a, d2.x); md##a = nma;                  \
      ma = fmaxf(ma, nma);                                                \
      const float nmb = fminf(md##b, d2.y); md##b = nmb;                  \
      mb = fmaxf(mb, nmb); }
      REP8P(FPS_UPDP)
#undef FPS_UPDP
      const float m = fmaxf(ma, mb);
      // exact tie index: min orig idx among this lane's md==m
      unsigned c = 0xFFFFFFFFu;
#define FPS_SCAN(j) c = (md##j == m) ? (ni##j < c ? ni##j : c) : c;
      REP16(FPS_SCAN)
#undef FPS_SCAN
      u64 k = ((u64)__float_as_uint(m) << 32) | (unsigned)(N_PTS - 1 - c);

      // wave max via DPP; lane 63 ends with the full wave max
      k = kmax_dpp<0xB1,  0xf>(k);   // quad_perm [1,0,3,2]
      k = kmax_dpp<0x4E,  0xf>(k);   // quad_perm [2,3,0,1]
      k = kmax_dpp<0x141, 0xf>(k);   // row_half_mirror (8-group)
      k = kmax_dpp<0x140, 0xf>(k);   // row_mirror      (16-group)
      k = kmax_dpp<0x142, 0xa>(k);   // row_bcast15 -> rows 1,3 (32-group)
      k = kmax_dpp<0x143, 0xc>(k);   // row_bcast31 -> rows 2,3 (64-group)
      wkk = k;

      // rebuild cached chunk prune threshold from LANE's chunk max m
      const float u = (cr + sqrtf(m * 1.0001f)) * 1.000003f;
      thr = u * u * 1.000001f;
    }

    const int par = s & 1;
    if (lane == 63) s_wkey[par][wid] = wkk;      // lane 63 holds wave max
    __syncthreads();                             // the ONLY barrier per step
    u64 kk = s_wkey[par][lane & 15];
    kk = kmax_dpp<0xB1,  0xf>(kk);
    kk = kmax_dpp<0x4E,  0xf>(kk);
    kk = kmax_dpp<0x141, 0xf>(kk);
    kk = kmax_dpp<0x140, 0xf>(kk);               // all lanes: block max

    const int oidx = (N_PTS - 1) - (int)(unsigned)(kk & 0xFFFFFFFFu);
    const float4 wpt = coords4[oidx];            // one uniform 16B load
    qx = wpt.x; qy = wpt.y; qz = wpt.z;
    if (tid == 0) {
      float* orow = out + (size_t)s * ROWF;
      orow[0] = qx; orow[1] = qy; orow[2] = qz;
    }
  }
}

// ---------------------------------------------------------------------------
// 4) KNN top-16 (ties -> lowest index) fused with feature max-pool.
// ---------------------------------------------------------------------------
__global__ __launch_bounds__(256)
void knn_pool_kernel(const float* __restrict__ x,
                     const float4* __restrict__ coords4,
                     float* __restrict__ out) {
  const int lane = threadIdx.x & 63;
  const int q = blockIdx.x * 4 + (threadIdx.x >> 6);

  const float qx = out[(size_t)q * ROWF + 0];
  const float qy = out[(size_t)q * ROWF + 1];
  const float qz = out[(size_t)q * ROWF + 2];

  u64 h[KNN];
#pragma unroll
  for (int k = 0; k < KNN; ++k) h[k] = ~0ULL;

  for (int c = lane; c < N_PTS; c += 64) {
    const float4 v = coords4[c];                 // coalesced 16B
    const float dx = v.x - qx, dy = v.y - qy, dz = v.z - qz;
    const float d2 = __fadd_rn(__fadd_rn(__fmul_rn(dx, dx), __fmul_rn(dy, dy)),
                               __fmul_rn(dz, dz));
    const u64 e = ((u64)__float_as_uint(d2) << 32) | (unsigned)c;
    if (e < h[KNN - 1]) {
#pragma unroll
      for (int k = KNN - 1; k >= 1; --k) {
        const u64 prev = h[k - 1];
        h[k] = (e < prev) ? prev : ((e < h[k]) ? e : h[k]);
      }
      h[0] = (e < h[0]) ? e : h[0];
    }
  }

  int nbr[KNN];
#pragma unroll
  for (int rr = 0; rr < KNN; ++rr) {
    u64 best = h[0];
#pragma unroll
    for (int off = 32; off; off >>= 1) {
      const u64 o = __shfl_xor(best, off);
      best = (o < best) ? o : best;
    }
    nbr[rr] = (int)(unsigned)(best & 0xffffffffULL);
    if (h[0] == best) {
#pragma unroll
      for (int k = 0; k < KNN - 1; ++k) h[k] = h[k + 1];
      h[KNN - 1] = ~0ULL;
    }
  }

  float a0 = __int_as_float(0xff800000), a1 = a0;
#pragma unroll
  for (int rr = 0; rr < KNN; ++rr) {
    const float* row = x + (size_t)nbr[rr] * ROWF + 3;
    a0 = fmaxf(a0, row[lane]);
    a1 = fmaxf(a1, row[lane + 64]);
  }
  float* orow = out + (size_t)q * ROWF + 3;
  orow[lane] = a0;
  orow[lane + 64] = a1;
}

extern "C" void kernel_launch(void* const* d_in, const int* in_sizes, int n_in,
                              void* d_out, int out_size, void* d_ws, size_t ws_size,
                              hipStream_t stream) {
  const float* x = (const float*)d_in[0];
  float* out = (float*)d_out;

  float4* coords4 = (float4*)d_ws;          // N float4 (256 KB)
  float4* gP4     = coords4 + N_PTS;        // N float4 (256 KB)

  hipLaunchKernelGGL(prep_kernel, dim3(64), dim3(256), 0, stream, x, coords4);
  hipLaunchKernelGGL(sort_kernel, dim3(1), dim3(1024), 0, stream, coords4, gP4);
  hipLaunchKernelGGL(fps_kernel, dim3(1), dim3(FPS_T), 0, stream,
                     coords4, gP4, out);
  hipLaunchKernelGGL(knn_pool_kernel, dim3(M_OUT / 4), dim3(256), 0, stream,
                     x, coords4, out);
}